// Round 1
// baseline (847.243 us; speedup 1.0000x reference)
//
#include <hip/hip_runtime.h>

#define K_IN   256   // IN
#define C_OUT  256   // H*OUT
#define HEADS  4

// ---------------------------------------------------------------------------
// GEMM: z[n][c] = sum_k h[n][k] * W[c][k]   (W row c = W[c/64][c%64][:])
// 128x128 tile, BK=64, 256 threads, 8x8 micro-tile (split 4+4 for
// conflict-free float4 LDS reads).
// ---------------------------------------------------------------------------
#define BN 128
#define BC 128
#define BK 64

__global__ __launch_bounds__(256) void gemm_z(const float* __restrict__ h,
                                              const float* __restrict__ Wm,
                                              float* __restrict__ z, int n_nodes) {
  __shared__ float hA[BK][BN];   // [k][n]
  __shared__ float wB[BK][BC];   // [k][c]
  const int tid = threadIdx.x;
  const int n0 = blockIdx.x * BN;
  const int c0 = blockIdx.y * BC;
  const int ty = tid >> 4;        // 0..15
  const int tx = tid & 15;        // 0..15
  float acc[8][8];
#pragma unroll
  for (int i = 0; i < 8; ++i)
#pragma unroll
    for (int j = 0; j < 8; ++j) acc[i][j] = 0.f;

  const int lr  = tid >> 4;        // 0..15
  const int lc4 = (tid & 15) * 4;  // 0..60

  for (int k0 = 0; k0 < K_IN; k0 += BK) {
#pragma unroll
    for (int rep = 0; rep < 8; ++rep) {
      int n = n0 + lr + rep * 16;
      float4 v = make_float4(0.f, 0.f, 0.f, 0.f);
      if (n < n_nodes) v = *reinterpret_cast<const float4*>(h + (size_t)n * K_IN + k0 + lc4);
      hA[lc4 + 0][lr + rep * 16] = v.x;
      hA[lc4 + 1][lr + rep * 16] = v.y;
      hA[lc4 + 2][lr + rep * 16] = v.z;
      hA[lc4 + 3][lr + rep * 16] = v.w;
    }
#pragma unroll
    for (int rep = 0; rep < 8; ++rep) {
      int c = c0 + lr + rep * 16;
      float4 v = *reinterpret_cast<const float4*>(Wm + (size_t)c * K_IN + k0 + lc4);
      wB[lc4 + 0][lr + rep * 16] = v.x;
      wB[lc4 + 1][lr + rep * 16] = v.y;
      wB[lc4 + 2][lr + rep * 16] = v.z;
      wB[lc4 + 3][lr + rep * 16] = v.w;
    }
    __syncthreads();
#pragma unroll 8
    for (int k = 0; k < BK; ++k) {
      float4 a0 = *reinterpret_cast<const float4*>(&hA[k][ty * 4]);
      float4 a1 = *reinterpret_cast<const float4*>(&hA[k][64 + ty * 4]);
      float4 b0 = *reinterpret_cast<const float4*>(&wB[k][tx * 4]);
      float4 b1 = *reinterpret_cast<const float4*>(&wB[k][64 + tx * 4]);
      float a[8] = {a0.x, a0.y, a0.z, a0.w, a1.x, a1.y, a1.z, a1.w};
      float b[8] = {b0.x, b0.y, b0.z, b0.w, b1.x, b1.y, b1.z, b1.w};
#pragma unroll
      for (int i = 0; i < 8; ++i)
#pragma unroll
        for (int j = 0; j < 8; ++j) acc[i][j] += a[i] * b[j];
    }
    __syncthreads();
  }
#pragma unroll
  for (int i = 0; i < 8; ++i) {
    int n = n0 + (i < 4 ? ty * 4 + i : 64 + ty * 4 + (i - 4));
    if (n < n_nodes) {
      float4 o0 = make_float4(acc[i][0], acc[i][1], acc[i][2], acc[i][3]);
      float4 o1 = make_float4(acc[i][4], acc[i][5], acc[i][6], acc[i][7]);
      *reinterpret_cast<float4*>(z + (size_t)n * C_OUT + c0 + tx * 4) = o0;
      *reinterpret_cast<float4*>(z + (size_t)n * C_OUT + c0 + 64 + tx * 4) = o1;
    }
  }
}

// ---------------------------------------------------------------------------
// s_src[n][h] = z[n][h*64:...] . a_src ; s_dst likewise. One wave per node.
// a_src = attn[0][0:64], a_dst = attn[0][64:128]  (reference uses attn[0] only)
// ---------------------------------------------------------------------------
__global__ __launch_bounds__(256) void s_kernel(const float* __restrict__ z,
                                                const float* __restrict__ attn,
                                                float* __restrict__ ssrc,
                                                float* __restrict__ sdst, int n_nodes) {
  int w = blockIdx.x * (blockDim.x >> 6) + (threadIdx.x >> 6);
  if (w >= n_nodes) return;
  int lane = threadIdx.x & 63;
  int head = lane >> 4;
  int o = (lane & 15) * 4;
  float4 zv = *reinterpret_cast<const float4*>(z + (size_t)w * C_OUT + lane * 4);
  float4 as = *reinterpret_cast<const float4*>(attn + o);
  float4 ad = *reinterpret_cast<const float4*>(attn + 64 + o);
  float ps = zv.x * as.x + zv.y * as.y + zv.z * as.z + zv.w * as.w;
  float pd = zv.x * ad.x + zv.y * ad.y + zv.z * ad.z + zv.w * ad.w;
#pragma unroll
  for (int d = 1; d < 16; d <<= 1) {
    ps += __shfl_xor(ps, d, 64);
    pd += __shfl_xor(pd, d, 64);
  }
  if ((lane & 15) == 0) {
    ssrc[w * 4 + head] = ps;
    sdst[w * 4 + head] = pd;
  }
}

// ---------------------------------------------------------------------------
// CSR build: zero counts -> histogram -> single-block scan -> scatter
// ---------------------------------------------------------------------------
__global__ void zero_counts(int* counts, int n) {
  int i = blockIdx.x * blockDim.x + threadIdx.x;
  if (i < n) counts[i] = 0;
}

__global__ void hist_kernel(const int* __restrict__ dst, int e, int* counts) {
  int i = blockIdx.x * blockDim.x + threadIdx.x;
  if (i < e) atomicAdd(&counts[dst[i]], 1);
}

__global__ __launch_bounds__(1024) void scan_kernel(const int* __restrict__ counts,
                                                    int* __restrict__ offs,
                                                    int* __restrict__ cursor,
                                                    int n, int total) {
  __shared__ int wsum[16];
  __shared__ int s_carry;
  const int t = threadIdx.x;
  const int lane = t & 63;
  const int wid = t >> 6;
  if (t == 0) s_carry = 0;
  __syncthreads();
  const int CH = 4096;
  for (int base = 0; base < n; base += CH) {
    int i0 = base + t * 4;
    int v[4];
    int s = 0;
#pragma unroll
    for (int j = 0; j < 4; ++j) {
      v[j] = (i0 + j < n) ? counts[i0 + j] : 0;
      s += v[j];
    }
    int incl = s;
#pragma unroll
    for (int d = 1; d < 64; d <<= 1) {
      int x = __shfl_up(incl, d, 64);
      if (lane >= d) incl += x;
    }
    if (lane == 63) wsum[wid] = incl;
    __syncthreads();
    int carry = s_carry;
    int wbase = 0;
    for (int wj = 0; wj < wid; ++wj) wbase += wsum[wj];
    int run = carry + wbase + incl - s;  // exclusive prefix for item 0
#pragma unroll
    for (int j = 0; j < 4; ++j) {
      int i = i0 + j;
      if (i < n) { offs[i] = run; cursor[i] = run; }
      run += v[j];
    }
    __syncthreads();
    if (t == blockDim.x - 1) s_carry = carry + wbase + incl;
    __syncthreads();
  }
  if (t == 0) offs[n] = total;
}

__global__ void scatter_kernel(const int* __restrict__ src, const int* __restrict__ dst,
                               int e, int* cursor, int* __restrict__ csr) {
  int i = blockIdx.x * blockDim.x + threadIdx.x;
  if (i < e) {
    int p = atomicAdd(&cursor[dst[i]], 1);
    csr[p] = src[i];
  }
}

// ---------------------------------------------------------------------------
// Aggregation: one wave per destination node. lane = output column / 4.
// head = lane>>4. Softmax shift-invariance lets us drop segment_max.
// ---------------------------------------------------------------------------
__global__ __launch_bounds__(256) void aggregate(const float* __restrict__ z,
                                                 const float* __restrict__ ssrc,
                                                 const float* __restrict__ sdst,
                                                 const int* __restrict__ offs,
                                                 const int* __restrict__ csr,
                                                 float* __restrict__ out, int n_nodes) {
  int w = blockIdx.x * (blockDim.x >> 6) + (threadIdx.x >> 6);
  if (w >= n_nodes) return;
  int lane = threadIdx.x & 63;
  int head = lane >> 4;
  int beg = offs[w];
  int end = offs[w + 1];
  float sd = sdst[(size_t)w * 4 + head];
  float ax = 0.f, ay = 0.f, az = 0.f, aw = 0.f;
  float den = 0.f;
  for (int e = beg; e < end; ++e) {
    int src = csr[e];
    float ss = ssrc[(size_t)src * 4 + head];
    float x = ss + sd;
    x = x > 0.f ? x : 0.01f * x;
    float ex = __expf(x);
    den += ex;
    float4 zv = *reinterpret_cast<const float4*>(z + (size_t)src * C_OUT + lane * 4);
    ax += ex * zv.x;
    ay += ex * zv.y;
    az += ex * zv.z;
    aw += ex * zv.w;
  }
  float inv = (end > beg) ? 1.f / fmaxf(den, 1e-9f) : 0.f;
  float4 o = make_float4(ax * inv, ay * inv, az * inv, aw * inv);
  *reinterpret_cast<float4*>(out + (size_t)w * C_OUT + lane * 4) = o;
}

// ---------------------------------------------------------------------------
extern "C" void kernel_launch(void* const* d_in, const int* in_sizes, int n_in,
                              void* d_out, int out_size, void* d_ws, size_t ws_size,
                              hipStream_t stream) {
  const float* h    = (const float*)d_in[0];
  const float* Wm   = (const float*)d_in[1];   // (H,OUT,IN) flat = (256,256)
  const float* attn = (const float*)d_in[2];   // (H, 128); only attn[0] used
  const int* e_src  = (const int*)d_in[3];
  const int* e_dst  = (const int*)d_in[4];
  float* out = (float*)d_out;

  const int N = in_sizes[0] / K_IN;
  const int E = in_sizes[3];

  char* p = (char*)d_ws;
  float* z    = (float*)p; p += (size_t)N * C_OUT * sizeof(float);
  float* ssrc = (float*)p; p += (size_t)N * HEADS * sizeof(float);
  float* sdst = (float*)p; p += (size_t)N * HEADS * sizeof(float);
  int* counts = (int*)p;   p += (size_t)N * sizeof(int);          // reused as cursor
  int* offs   = (int*)p;   p += (size_t)(N + 4) * sizeof(int);
  int* csr    = (int*)p;   p += (size_t)E * sizeof(int);

  // 1) z = h @ W^T
  dim3 ggrid((N + BN - 1) / BN, C_OUT / BC);
  hipLaunchKernelGGL(gemm_z, ggrid, dim3(256), 0, stream, h, Wm, z, N);

  // 2) per-node scores
  int sblocks = (N + 3) / 4;
  hipLaunchKernelGGL(s_kernel, dim3(sblocks), dim3(256), 0, stream, z, attn, ssrc, sdst, N);

  // 3) CSR build by destination
  hipLaunchKernelGGL(zero_counts, dim3((N + 255) / 256), dim3(256), 0, stream, counts, N);
  hipLaunchKernelGGL(hist_kernel, dim3((E + 255) / 256), dim3(256), 0, stream, e_dst, E, counts);
  hipLaunchKernelGGL(scan_kernel, dim3(1), dim3(1024), 0, stream, counts, offs, counts, N, E);
  hipLaunchKernelGGL(scatter_kernel, dim3((E + 255) / 256), dim3(256), 0, stream, e_src, e_dst, E, counts, csr);

  // 4) softmax-weighted aggregation, one wave per node
  hipLaunchKernelGGL(aggregate, dim3((N + 3) / 4), dim3(256), 0, stream,
                     z, ssrc, sdst, offs, csr, out, N);
}

// Round 2
// 607.628 us; speedup vs baseline: 1.3943x; 1.3943x over previous
//
#include <hip/hip_runtime.h>

#define K_IN   256   // IN
#define C_OUT  256   // H*OUT
#define HEADS  4

typedef __attribute__((ext_vector_type(8))) short s16x8;
typedef __attribute__((ext_vector_type(4))) float f32x4;

static __device__ __forceinline__ unsigned short f2bf(float f) {
  union { float f; unsigned u; } v; v.f = f;
  unsigned r = v.u + 0x7FFFu + ((v.u >> 16) & 1u);
  return (unsigned short)(r >> 16);
}

// ---------------------------------------------------------------------------
// Convert h (fp32) -> bf16, stored aliased in the SECOND half of each z row:
// z row n is 512 ushorts; bf16 h row n lives at ushort offset n*512 + 256.
// Block i of the GEMM reads only its own rows, and stores to z only after a
// __syncthreads() that follows all A-fragment loads -> no race.
// ---------------------------------------------------------------------------
__global__ void cvt_h(const float* __restrict__ h, unsigned short* __restrict__ zu,
                      long long n8) {
  long long i = (long long)blockIdx.x * blockDim.x + threadIdx.x;
  long long stride = (long long)gridDim.x * blockDim.x;
  for (; i < n8; i += stride) {
    long long n = i >> 5;          // row
    int k = (int)(i & 31) * 8;     // col group of 8
    const float4* p = reinterpret_cast<const float4*>(h + n * K_IN + k);
    float4 a = p[0], b = p[1];
    s16x8 o;
    o[0] = (short)f2bf(a.x); o[1] = (short)f2bf(a.y);
    o[2] = (short)f2bf(a.z); o[3] = (short)f2bf(a.w);
    o[4] = (short)f2bf(b.x); o[5] = (short)f2bf(b.y);
    o[6] = (short)f2bf(b.z); o[7] = (short)f2bf(b.w);
    *reinterpret_cast<s16x8*>(zu + n * 512 + 256 + k) = o;
  }
}

// ---------------------------------------------------------------------------
// Convert W (fp32, [c=256][k=256] where c = head*64+out) into fragment-ordered
// bf16: Wf[((cb*8+ks)*4+s)*512 + lane*8 + j] = W[cb*64+s*16+(lane&15)]
//                                               [ks*32+(lane>>4)*8+j]
// so each B-fragment load in the GEMM is one fully-coalesced 1 KB wave read.
// ---------------------------------------------------------------------------
__global__ void cvt_w(const float* __restrict__ Wm, unsigned short* __restrict__ Wf) {
  int idx = blockIdx.x * blockDim.x + threadIdx.x;
  if (idx >= 65536) return;
  int j    = idx & 7;
  int lane = (idx >> 3) & 63;
  int s    = (idx >> 9) & 3;
  int ks   = (idx >> 11) & 7;
  int cb   = (idx >> 14) & 3;
  int c = cb * 64 + s * 16 + (lane & 15);
  int k = ks * 32 + (lane >> 4) * 8 + j;
  Wf[idx] = f2bf(Wm[c * K_IN + k]);
}

// ---------------------------------------------------------------------------
// GEMM: z[n][c] = sum_k h[n][k] * W[c][k] via bf16 MFMA 16x16x32.
// Block = 256 threads = 4 waves; block tile = 64 nodes x 256 cols; wave w
// owns cols w*64..w*64+63 as 4x4 fragments. No LDS, no K-loop barriers.
// ---------------------------------------------------------------------------
__global__ __launch_bounds__(256) void gemm_z(const unsigned short* __restrict__ zu,
                                              const unsigned short* __restrict__ Wf,
                                              float* __restrict__ z, int n_nodes) {
  const int wid  = threadIdx.x >> 6;   // col block 0..3
  const int lane = threadIdx.x & 63;
  const int l15  = lane & 15;
  const int lhi  = lane >> 4;          // 0..3
  const int m0   = blockIdx.x * 64;

  f32x4 acc[4][4];
#pragma unroll
  for (int r = 0; r < 4; ++r)
#pragma unroll
    for (int s = 0; s < 4; ++s) acc[r][s] = (f32x4){0.f, 0.f, 0.f, 0.f};

  long long arow[4];
#pragma unroll
  for (int r = 0; r < 4; ++r) {
    int n = m0 + r * 16 + l15;
    if (n > n_nodes - 1) n = n_nodes - 1;
    arow[r] = (long long)n * 512 + 256;  // ushort offset of bf16 h row n
  }
  const int kbase = lhi * 8;

#pragma unroll
  for (int ks = 0; ks < 8; ++ks) {
    const int k = ks * 32 + kbase;
    s16x8 a[4], b[4];
#pragma unroll
    for (int r = 0; r < 4; ++r)
      a[r] = *reinterpret_cast<const s16x8*>(zu + arow[r] + k);
#pragma unroll
    for (int s = 0; s < 4; ++s)
      b[s] = *reinterpret_cast<const s16x8*>(Wf + ((wid * 8 + ks) * 4 + s) * 512 + lane * 8);
#pragma unroll
    for (int r = 0; r < 4; ++r)
#pragma unroll
      for (int s = 0; s < 4; ++s)
        acc[r][s] = __builtin_amdgcn_mfma_f32_16x16x32_bf16(a[r], b[s], acc[r][s], 0, 0, 0);
  }

  __syncthreads();  // all waves done reading aliased bf16 h before overwriting z

  const int c0 = wid * 64;
#pragma unroll
  for (int r = 0; r < 4; ++r) {
    int rowbase = m0 + r * 16 + lhi * 4;
#pragma unroll
    for (int s = 0; s < 4; ++s) {
#pragma unroll
      for (int reg = 0; reg < 4; ++reg) {
        int row = rowbase + reg;
        if (row < n_nodes)
          z[(size_t)row * C_OUT + c0 + s * 16 + l15] = acc[r][s][reg];
      }
    }
  }
}

// ---------------------------------------------------------------------------
// s_src[n][h] = z[n][h*64:...] . a_src ; s_dst likewise. One wave per node.
// ---------------------------------------------------------------------------
__global__ __launch_bounds__(256) void s_kernel(const float* __restrict__ z,
                                                const float* __restrict__ attn,
                                                float* __restrict__ ssrc,
                                                float* __restrict__ sdst, int n_nodes) {
  int w = blockIdx.x * (blockDim.x >> 6) + (threadIdx.x >> 6);
  if (w >= n_nodes) return;
  int lane = threadIdx.x & 63;
  int head = lane >> 4;
  int o = (lane & 15) * 4;
  float4 zv = *reinterpret_cast<const float4*>(z + (size_t)w * C_OUT + lane * 4);
  float4 as = *reinterpret_cast<const float4*>(attn + o);
  float4 ad = *reinterpret_cast<const float4*>(attn + 64 + o);
  float ps = zv.x * as.x + zv.y * as.y + zv.z * as.z + zv.w * as.w;
  float pd = zv.x * ad.x + zv.y * ad.y + zv.z * ad.z + zv.w * ad.w;
#pragma unroll
  for (int d = 1; d < 16; d <<= 1) {
    ps += __shfl_xor(ps, d, 64);
    pd += __shfl_xor(pd, d, 64);
  }
  if ((lane & 15) == 0) {
    ssrc[w * 4 + head] = ps;
    sdst[w * 4 + head] = pd;
  }
}

// ---------------------------------------------------------------------------
// CSR build: zero counts -> histogram -> single-block scan -> scatter
// ---------------------------------------------------------------------------
__global__ void zero_counts(int* counts, int n) {
  int i = blockIdx.x * blockDim.x + threadIdx.x;
  if (i < n) counts[i] = 0;
}

__global__ void hist_kernel(const int* __restrict__ dst, int e, int* counts) {
  int i = blockIdx.x * blockDim.x + threadIdx.x;
  if (i < e) atomicAdd(&counts[dst[i]], 1);
}

__global__ __launch_bounds__(1024) void scan_kernel(const int* __restrict__ counts,
                                                    int* __restrict__ offs,
                                                    int* __restrict__ cursor,
                                                    int n, int total) {
  __shared__ int wsum[16];
  __shared__ int s_carry;
  const int t = threadIdx.x;
  const int lane = t & 63;
  const int wid = t >> 6;
  if (t == 0) s_carry = 0;
  __syncthreads();
  const int CH = 4096;
  for (int base = 0; base < n; base += CH) {
    int i0 = base + t * 4;
    int v[4];
    int s = 0;
#pragma unroll
    for (int j = 0; j < 4; ++j) {
      v[j] = (i0 + j < n) ? counts[i0 + j] : 0;
      s += v[j];
    }
    int incl = s;
#pragma unroll
    for (int d = 1; d < 64; d <<= 1) {
      int x = __shfl_up(incl, d, 64);
      if (lane >= d) incl += x;
    }
    if (lane == 63) wsum[wid] = incl;
    __syncthreads();
    int carry = s_carry;
    int wbase = 0;
    for (int wj = 0; wj < wid; ++wj) wbase += wsum[wj];
    int run = carry + wbase + incl - s;
#pragma unroll
    for (int j = 0; j < 4; ++j) {
      int i = i0 + j;
      if (i < n) { offs[i] = run; cursor[i] = run; }
      run += v[j];
    }
    __syncthreads();
    if (t == blockDim.x - 1) s_carry = carry + wbase + incl;
    __syncthreads();
  }
  if (t == 0) offs[n] = total;
}

__global__ void scatter_kernel(const int* __restrict__ src, const int* __restrict__ dst,
                               int e, int* cursor, int* __restrict__ csr) {
  int i = blockIdx.x * blockDim.x + threadIdx.x;
  if (i < e) {
    int p = atomicAdd(&cursor[dst[i]], 1);
    csr[p] = src[i];
  }
}

// ---------------------------------------------------------------------------
// Aggregation: one wave per destination node.
// ---------------------------------------------------------------------------
__global__ __launch_bounds__(256) void aggregate(const float* __restrict__ z,
                                                 const float* __restrict__ ssrc,
                                                 const float* __restrict__ sdst,
                                                 const int* __restrict__ offs,
                                                 const int* __restrict__ csr,
                                                 float* __restrict__ out, int n_nodes) {
  int w = blockIdx.x * (blockDim.x >> 6) + (threadIdx.x >> 6);
  if (w >= n_nodes) return;
  int lane = threadIdx.x & 63;
  int head = lane >> 4;
  int beg = offs[w];
  int end = offs[w + 1];
  float sd = sdst[(size_t)w * 4 + head];
  float ax = 0.f, ay = 0.f, az = 0.f, aw = 0.f;
  float den = 0.f;
  for (int e = beg; e < end; ++e) {
    int src = csr[e];
    float ss = ssrc[(size_t)src * 4 + head];
    float x = ss + sd;
    x = x > 0.f ? x : 0.01f * x;
    float ex = __expf(x);
    den += ex;
    float4 zv = *reinterpret_cast<const float4*>(z + (size_t)src * C_OUT + lane * 4);
    ax += ex * zv.x;
    ay += ex * zv.y;
    az += ex * zv.z;
    aw += ex * zv.w;
  }
  float inv = (end > beg) ? 1.f / fmaxf(den, 1e-9f) : 0.f;
  float4 o = make_float4(ax * inv, ay * inv, az * inv, aw * inv);
  *reinterpret_cast<float4*>(out + (size_t)w * C_OUT + lane * 4) = o;
}

// ---------------------------------------------------------------------------
extern "C" void kernel_launch(void* const* d_in, const int* in_sizes, int n_in,
                              void* d_out, int out_size, void* d_ws, size_t ws_size,
                              hipStream_t stream) {
  const float* h    = (const float*)d_in[0];
  const float* Wm   = (const float*)d_in[1];   // (H,OUT,IN) flat = (256,256)
  const float* attn = (const float*)d_in[2];   // (H, 128); only attn[0] used
  const int* e_src  = (const int*)d_in[3];
  const int* e_dst  = (const int*)d_in[4];
  float* out = (float*)d_out;

  const int N = in_sizes[0] / K_IN;
  const int E = in_sizes[3];

  char* p = (char*)d_ws;
  float* z    = (float*)p; p += (size_t)N * C_OUT * sizeof(float);
  float* ssrc = (float*)p; p += (size_t)N * HEADS * sizeof(float);
  float* sdst = (float*)p; p += (size_t)N * HEADS * sizeof(float);
  int* counts = (int*)p;   p += (size_t)N * sizeof(int);          // reused as cursor
  int* offs   = (int*)p;   p += (size_t)(N + 4) * sizeof(int);
  int* csr    = (int*)p;   p += (size_t)E * sizeof(int);
  unsigned short* Wf = (unsigned short*)p; p += 65536 * sizeof(unsigned short);
  unsigned short* zu = (unsigned short*)z;  // bf16 h aliased into z rows

  // 0) conversions
  hipLaunchKernelGGL(cvt_h, dim3(2048), dim3(256), 0, stream, h, zu, (long long)N * 32);
  hipLaunchKernelGGL(cvt_w, dim3(256), dim3(256), 0, stream, Wm, Wf);

  // 1) z = h @ W^T  (bf16 MFMA)
  hipLaunchKernelGGL(gemm_z, dim3((N + 63) / 64), dim3(256), 0, stream, zu, Wf, z, N);

  // 2) per-node scores
  hipLaunchKernelGGL(s_kernel, dim3((N + 3) / 4), dim3(256), 0, stream, z, attn, ssrc, sdst, N);

  // 3) CSR build by destination
  hipLaunchKernelGGL(zero_counts, dim3((N + 255) / 256), dim3(256), 0, stream, counts, N);
  hipLaunchKernelGGL(hist_kernel, dim3((E + 255) / 256), dim3(256), 0, stream, e_dst, E, counts);
  hipLaunchKernelGGL(scan_kernel, dim3(1), dim3(1024), 0, stream, counts, offs, counts, N, E);
  hipLaunchKernelGGL(scatter_kernel, dim3((E + 255) / 256), dim3(256), 0, stream, e_src, e_dst, E, counts, csr);

  // 4) softmax-weighted aggregation, one wave per node
  hipLaunchKernelGGL(aggregate, dim3((N + 3) / 4), dim3(256), 0, stream,
                     z, ssrc, sdst, offs, csr, out, N);
}

// Round 3
// 533.725 us; speedup vs baseline: 1.5874x; 1.1385x over previous
//
#include <hip/hip_runtime.h>

#define K_IN   256   // IN
#define C_OUT  256   // H*OUT
#define HEADS  4

typedef __attribute__((ext_vector_type(8))) short s16x8;
typedef __attribute__((ext_vector_type(4))) short s16x4;
typedef __attribute__((ext_vector_type(4))) float f32x4;

static __device__ __forceinline__ unsigned short f2bf(float f) {
  union { float f; unsigned u; } v; v.f = f;
  unsigned r = v.u + 0x7FFFu + ((v.u >> 16) & 1u);
  return (unsigned short)(r >> 16);
}
static __device__ __forceinline__ float bf2f(unsigned short u) {
  union { unsigned u; float f; } v; v.u = (unsigned)u << 16;
  return v.f;
}

// ---------------------------------------------------------------------------
// Convert h (fp32) -> bf16 staging buffer hb[n][k].
// ---------------------------------------------------------------------------
__global__ void cvt_h(const float* __restrict__ h, unsigned short* __restrict__ hb,
                      long long n8) {
  long long i = (long long)blockIdx.x * blockDim.x + threadIdx.x;
  long long stride = (long long)gridDim.x * blockDim.x;
  for (; i < n8; i += stride) {
    long long n = i >> 5;          // row
    int k = (int)(i & 31) * 8;     // col group of 8
    const float4* p = reinterpret_cast<const float4*>(h + n * K_IN + k);
    float4 a = p[0], b = p[1];
    s16x8 o;
    o[0] = (short)f2bf(a.x); o[1] = (short)f2bf(a.y);
    o[2] = (short)f2bf(a.z); o[3] = (short)f2bf(a.w);
    o[4] = (short)f2bf(b.x); o[5] = (short)f2bf(b.y);
    o[6] = (short)f2bf(b.z); o[7] = (short)f2bf(b.w);
    *reinterpret_cast<s16x8*>(hb + n * K_IN + k) = o;
  }
}

// ---------------------------------------------------------------------------
// Convert W (fp32, [c=256][k=256], c = head*64+out) into fragment-ordered bf16:
// Wf[((cb*8+ks)*4+s)*512 + lane*8 + j] = W[cb*64+s*16+(lane&15)][ks*32+(lane>>4)*8+j]
// ---------------------------------------------------------------------------
__global__ void cvt_w(const float* __restrict__ Wm, unsigned short* __restrict__ Wf) {
  int idx = blockIdx.x * blockDim.x + threadIdx.x;
  if (idx >= 65536) return;
  int j    = idx & 7;
  int lane = (idx >> 3) & 63;
  int s    = (idx >> 9) & 3;
  int ks   = (idx >> 11) & 7;
  int cb   = (idx >> 14) & 3;
  int c = cb * 64 + s * 16 + (lane & 15);
  int k = ks * 32 + (lane >> 4) * 8 + j;
  Wf[idx] = f2bf(Wm[c * K_IN + k]);
}

// ---------------------------------------------------------------------------
// GEMM: z[n][c] = sum_k h[n][k] * W[c][k] via bf16 MFMA 16x16x32.
// Block = 4 waves; tile = 64 nodes x 256 cols; wave w owns head w's 64 cols.
// Epilogue: writes bf16 z AND the per-head attention scores
//   ssrc[n][w] = z[n, w*64:(w+1)*64] . attn[0:64]
//   sdst[n][w] = z[n, w*64:(w+1)*64] . attn[64:128]
// computed in-register from the fp32 accumulators (full precision).
// ---------------------------------------------------------------------------
__global__ __launch_bounds__(256) void gemm_z(const unsigned short* __restrict__ hb,
                                              const unsigned short* __restrict__ Wf,
                                              const float* __restrict__ attn,
                                              unsigned short* __restrict__ zb,
                                              float* __restrict__ ssrc,
                                              float* __restrict__ sdst, int n_nodes) {
  const int wid  = threadIdx.x >> 6;   // col block == head, 0..3
  const int lane = threadIdx.x & 63;
  const int l15  = lane & 15;
  const int lhi  = lane >> 4;          // 0..3
  const int m0   = blockIdx.x * 64;

  f32x4 acc[4][4];
#pragma unroll
  for (int r = 0; r < 4; ++r)
#pragma unroll
    for (int s = 0; s < 4; ++s) acc[r][s] = (f32x4){0.f, 0.f, 0.f, 0.f};

  long long arow[4];
#pragma unroll
  for (int r = 0; r < 4; ++r) {
    int n = m0 + r * 16 + l15;
    if (n > n_nodes - 1) n = n_nodes - 1;
    arow[r] = (long long)n * K_IN;
  }
  const int kbase = lhi * 8;

#pragma unroll
  for (int ks = 0; ks < 8; ++ks) {
    const int k = ks * 32 + kbase;
    s16x8 a[4], b[4];
#pragma unroll
    for (int r = 0; r < 4; ++r)
      a[r] = *reinterpret_cast<const s16x8*>(hb + arow[r] + k);
#pragma unroll
    for (int s = 0; s < 4; ++s)
      b[s] = *reinterpret_cast<const s16x8*>(Wf + ((wid * 8 + ks) * 4 + s) * 512 + lane * 8);
#pragma unroll
    for (int r = 0; r < 4; ++r)
#pragma unroll
      for (int s = 0; s < 4; ++s)
        acc[r][s] = __builtin_amdgcn_mfma_f32_16x16x32_bf16(a[r], b[s], acc[r][s], 0, 0, 0);
  }

  // ---- epilogue 1: bf16 z store ----
#pragma unroll
  for (int r = 0; r < 4; ++r) {
#pragma unroll
    for (int reg = 0; reg < 4; ++reg) {
      int row = m0 + r * 16 + lhi * 4 + reg;
      if (row < n_nodes) {
#pragma unroll
        for (int s = 0; s < 4; ++s)
          zb[(size_t)row * C_OUT + wid * 64 + s * 16 + l15] = f2bf(acc[r][s][reg]);
      }
    }
  }

  // ---- epilogue 2: attention scores (fp32, in-register) ----
  float as_[4], ad_[4];
#pragma unroll
  for (int s = 0; s < 4; ++s) {
    as_[s] = attn[s * 16 + l15];
    ad_[s] = attn[64 + s * 16 + l15];
  }
#pragma unroll
  for (int r = 0; r < 4; ++r) {
#pragma unroll
    for (int reg = 0; reg < 4; ++reg) {
      float ps = acc[r][0][reg] * as_[0] + acc[r][1][reg] * as_[1] +
                 acc[r][2][reg] * as_[2] + acc[r][3][reg] * as_[3];
      float pd = acc[r][0][reg] * ad_[0] + acc[r][1][reg] * ad_[1] +
                 acc[r][2][reg] * ad_[2] + acc[r][3][reg] * ad_[3];
#pragma unroll
      for (int d = 1; d < 16; d <<= 1) {
        ps += __shfl_xor(ps, d, 64);
        pd += __shfl_xor(pd, d, 64);
      }
      if (l15 == 0) {
        int row = m0 + r * 16 + lhi * 4 + reg;
        if (row < n_nodes) {
          ssrc[(size_t)row * 4 + wid] = ps;
          sdst[(size_t)row * 4 + wid] = pd;
        }
      }
    }
  }
}

// ---------------------------------------------------------------------------
// CSR build: zero counts -> histogram -> single-block scan -> scatter
// ---------------------------------------------------------------------------
__global__ void zero_counts(int* counts, int n) {
  int i = blockIdx.x * blockDim.x + threadIdx.x;
  if (i < n) counts[i] = 0;
}

__global__ void hist_kernel(const int* __restrict__ dst, int e, int* counts) {
  int i = blockIdx.x * blockDim.x + threadIdx.x;
  if (i < e) atomicAdd(&counts[dst[i]], 1);
}

__global__ __launch_bounds__(1024) void scan_kernel(const int* __restrict__ counts,
                                                    int* __restrict__ offs,
                                                    int* __restrict__ cursor,
                                                    int n, int total) {
  __shared__ int wsum[16];
  __shared__ int s_carry;
  const int t = threadIdx.x;
  const int lane = t & 63;
  const int wid = t >> 6;
  if (t == 0) s_carry = 0;
  __syncthreads();
  const int CH = 4096;
  for (int base = 0; base < n; base += CH) {
    int i0 = base + t * 4;
    int v[4];
    int s = 0;
#pragma unroll
    for (int j = 0; j < 4; ++j) {
      v[j] = (i0 + j < n) ? counts[i0 + j] : 0;
      s += v[j];
    }
    int incl = s;
#pragma unroll
    for (int d = 1; d < 64; d <<= 1) {
      int x = __shfl_up(incl, d, 64);
      if (lane >= d) incl += x;
    }
    if (lane == 63) wsum[wid] = incl;
    __syncthreads();
    int carry = s_carry;
    int wbase = 0;
    for (int wj = 0; wj < wid; ++wj) wbase += wsum[wj];
    int run = carry + wbase + incl - s;
#pragma unroll
    for (int j = 0; j < 4; ++j) {
      int i = i0 + j;
      if (i < n) { offs[i] = run; cursor[i] = run; }
      run += v[j];
    }
    __syncthreads();
    if (t == blockDim.x - 1) s_carry = carry + wbase + incl;
    __syncthreads();
  }
  if (t == 0) offs[n] = total;
}

__global__ void scatter_kernel(const int* __restrict__ src, const int* __restrict__ dst,
                               int e, int* cursor, int* __restrict__ csr) {
  int i = blockIdx.x * blockDim.x + threadIdx.x;
  if (i < e) {
    int p = atomicAdd(&cursor[dst[i]], 1);
    csr[p] = src[i];
  }
}

// ---------------------------------------------------------------------------
// Aggregation: one wave per destination node; bf16 z gather (512 B/edge).
// Softmax shift-invariance lets us drop segment_max (values bounded).
// ---------------------------------------------------------------------------
__global__ __launch_bounds__(256) void aggregate(const unsigned short* __restrict__ zb,
                                                 const float* __restrict__ ssrc,
                                                 const float* __restrict__ sdst,
                                                 const int* __restrict__ offs,
                                                 const int* __restrict__ csr,
                                                 float* __restrict__ out, int n_nodes) {
  int w = blockIdx.x * (blockDim.x >> 6) + (threadIdx.x >> 6);
  if (w >= n_nodes) return;
  int lane = threadIdx.x & 63;
  int head = lane >> 4;
  int beg = offs[w];
  int end = offs[w + 1];
  float sd = sdst[(size_t)w * 4 + head];
  float ax = 0.f, ay = 0.f, az = 0.f, aw = 0.f;
  float den = 0.f;
  for (int e = beg; e < end; ++e) {
    int src = csr[e];
    float ss = ssrc[(size_t)src * 4 + head];
    float x = ss + sd;
    x = x > 0.f ? x : 0.01f * x;
    float ex = __expf(x);
    den += ex;
    s16x4 zv = *reinterpret_cast<const s16x4*>(zb + (size_t)src * C_OUT + lane * 4);
    ax += ex * bf2f((unsigned short)zv[0]);
    ay += ex * bf2f((unsigned short)zv[1]);
    az += ex * bf2f((unsigned short)zv[2]);
    aw += ex * bf2f((unsigned short)zv[3]);
  }
  float inv = (end > beg) ? 1.f / fmaxf(den, 1e-9f) : 0.f;
  float4 o = make_float4(ax * inv, ay * inv, az * inv, aw * inv);
  *reinterpret_cast<float4*>(out + (size_t)w * C_OUT + lane * 4) = o;
}

// ---------------------------------------------------------------------------
extern "C" void kernel_launch(void* const* d_in, const int* in_sizes, int n_in,
                              void* d_out, int out_size, void* d_ws, size_t ws_size,
                              hipStream_t stream) {
  const float* h    = (const float*)d_in[0];
  const float* Wm   = (const float*)d_in[1];   // (H,OUT,IN) flat = (256,256)
  const float* attn = (const float*)d_in[2];   // (H, 128); only attn[0] used
  const int* e_src  = (const int*)d_in[3];
  const int* e_dst  = (const int*)d_in[4];
  float* out = (float*)d_out;

  const int N = in_sizes[0] / K_IN;
  const int E = in_sizes[3];

  // Workspace layout. CSR buffers alias hb (bf16 h staging): hb is dead after
  // gemm_z, and the CSR kernels run after gemm_z in stream order.
  char* p = (char*)d_ws;
  unsigned short* hb = (unsigned short*)p;           // N*256 bf16 = 51.2 MB
  int* counts = (int*)p;   p += (size_t)N * sizeof(int);        // aliases hb
  int* offs   = (int*)p;   p += (size_t)(N + 4) * sizeof(int);  // aliases hb
  int* csr    = (int*)p;                                        // aliases hb
  p = (char*)d_ws + (size_t)N * K_IN * sizeof(unsigned short);
  unsigned short* zb = (unsigned short*)p; p += (size_t)N * C_OUT * sizeof(unsigned short);
  float* ssrc = (float*)p; p += (size_t)N * HEADS * sizeof(float);
  float* sdst = (float*)p; p += (size_t)N * HEADS * sizeof(float);
  unsigned short* Wf = (unsigned short*)p; p += 65536 * sizeof(unsigned short);

  // 0) conversions
  hipLaunchKernelGGL(cvt_h, dim3(2048), dim3(256), 0, stream, h, hb, (long long)N * 32);
  hipLaunchKernelGGL(cvt_w, dim3(256), dim3(256), 0, stream, Wm, Wf);

  // 1) z = h @ W^T (bf16 MFMA) + fused score epilogue
  hipLaunchKernelGGL(gemm_z, dim3((N + 63) / 64), dim3(256), 0, stream,
                     hb, Wf, attn, zb, ssrc, sdst, N);

  // 2) CSR build by destination (overwrites hb region — after gemm_z)
  hipLaunchKernelGGL(zero_counts, dim3((N + 255) / 256), dim3(256), 0, stream, counts, N);
  hipLaunchKernelGGL(hist_kernel, dim3((E + 255) / 256), dim3(256), 0, stream, e_dst, E, counts);
  hipLaunchKernelGGL(scan_kernel, dim3(1), dim3(1024), 0, stream, counts, offs, counts, N, E);
  hipLaunchKernelGGL(scatter_kernel, dim3((E + 255) / 256), dim3(256), 0, stream, e_src, e_dst, E, counts, csr);

  // 3) softmax-weighted aggregation, one wave per node
  hipLaunchKernelGGL(aggregate, dim3((N + 3) / 4), dim3(256), 0, stream,
                     zb, ssrc, sdst, offs, csr, out, N);
}

// Round 4
// 440.011 us; speedup vs baseline: 1.9255x; 1.2130x over previous
//
#include <hip/hip_runtime.h>

#define K_IN   256   // IN
#define C_OUT  256   // H*OUT
#define HEADS  4

typedef __attribute__((ext_vector_type(8))) short s16x8;
typedef __attribute__((ext_vector_type(4))) short s16x4;
typedef __attribute__((ext_vector_type(4))) float f32x4;

static __device__ __forceinline__ unsigned short f2bf(float f) {
  union { float f; unsigned u; } v; v.f = f;
  unsigned r = v.u + 0x7FFFu + ((v.u >> 16) & 1u);
  return (unsigned short)(r >> 16);
}
static __device__ __forceinline__ float bf2f(unsigned short u) {
  union { unsigned u; float f; } v; v.u = (unsigned)u << 16;
  return v.f;
}

// ---------------------------------------------------------------------------
// Convert W (fp32, [c=256][k=256], c = head*64+out) into fragment-ordered bf16:
// Wf[((cb*8+ks)*4+s)*512 + lane*8 + j] = W[cb*64+s*16+(lane&15)][ks*32+(lane>>4)*8+j]
// ---------------------------------------------------------------------------
__global__ void cvt_w(const float* __restrict__ Wm, unsigned short* __restrict__ Wf) {
  int idx = blockIdx.x * blockDim.x + threadIdx.x;
  if (idx >= 65536) return;
  int j    = idx & 7;
  int lane = (idx >> 3) & 63;
  int s    = (idx >> 9) & 3;
  int ks   = (idx >> 11) & 7;
  int cb   = (idx >> 14) & 3;
  int c = cb * 64 + s * 16 + (lane & 15);
  int k = ks * 32 + (lane >> 4) * 8 + j;
  Wf[idx] = f2bf(Wm[c * K_IN + k]);
}

// ---------------------------------------------------------------------------
// GEMM: z[n][c] = sum_k h[n][k] * W[c][k] via bf16 MFMA 16x16x32.
// Reads fp32 h directly; converts A-fragments to bf16 in-register.
// Block = 4 waves; tile = 64 nodes x 256 cols; wave w owns head w's 64 cols.
// Epilogue: bf16 z store + in-register attention scores.
// ---------------------------------------------------------------------------
__global__ __launch_bounds__(256) void gemm_z(const float* __restrict__ h,
                                              const unsigned short* __restrict__ Wf,
                                              const float* __restrict__ attn,
                                              unsigned short* __restrict__ zb,
                                              float* __restrict__ ssrc,
                                              float* __restrict__ sdst, int n_nodes) {
  const int wid  = threadIdx.x >> 6;   // col block == head, 0..3
  const int lane = threadIdx.x & 63;
  const int l15  = lane & 15;
  const int lhi  = lane >> 4;          // 0..3
  const int m0   = blockIdx.x * 64;

  f32x4 acc[4][4];
#pragma unroll
  for (int r = 0; r < 4; ++r)
#pragma unroll
    for (int s = 0; s < 4; ++s) acc[r][s] = (f32x4){0.f, 0.f, 0.f, 0.f};

  long long arow[4];
#pragma unroll
  for (int r = 0; r < 4; ++r) {
    int n = m0 + r * 16 + l15;
    if (n > n_nodes - 1) n = n_nodes - 1;
    arow[r] = (long long)n * K_IN;
  }
  const int kbase = lhi * 8;

#pragma unroll
  for (int ks = 0; ks < 8; ++ks) {
    const int k = ks * 32 + kbase;
    s16x8 a[4], b[4];
#pragma unroll
    for (int r = 0; r < 4; ++r) {
      const float4* p = reinterpret_cast<const float4*>(h + arow[r] + k);
      float4 v0 = p[0], v1 = p[1];
      a[r][0] = (short)f2bf(v0.x); a[r][1] = (short)f2bf(v0.y);
      a[r][2] = (short)f2bf(v0.z); a[r][3] = (short)f2bf(v0.w);
      a[r][4] = (short)f2bf(v1.x); a[r][5] = (short)f2bf(v1.y);
      a[r][6] = (short)f2bf(v1.z); a[r][7] = (short)f2bf(v1.w);
    }
#pragma unroll
    for (int s = 0; s < 4; ++s)
      b[s] = *reinterpret_cast<const s16x8*>(Wf + ((wid * 8 + ks) * 4 + s) * 512 + lane * 8);
#pragma unroll
    for (int r = 0; r < 4; ++r)
#pragma unroll
      for (int s = 0; s < 4; ++s)
        acc[r][s] = __builtin_amdgcn_mfma_f32_16x16x32_bf16(a[r], b[s], acc[r][s], 0, 0, 0);
  }

  // ---- epilogue 1: bf16 z store ----
#pragma unroll
  for (int r = 0; r < 4; ++r) {
#pragma unroll
    for (int reg = 0; reg < 4; ++reg) {
      int row = m0 + r * 16 + lhi * 4 + reg;
      if (row < n_nodes) {
#pragma unroll
        for (int s = 0; s < 4; ++s)
          zb[(size_t)row * C_OUT + wid * 64 + s * 16 + l15] = f2bf(acc[r][s][reg]);
      }
    }
  }

  // ---- epilogue 2: attention scores (fp32, in-register) ----
  float as_[4], ad_[4];
#pragma unroll
  for (int s = 0; s < 4; ++s) {
    as_[s] = attn[s * 16 + l15];
    ad_[s] = attn[64 + s * 16 + l15];
  }
#pragma unroll
  for (int r = 0; r < 4; ++r) {
#pragma unroll
    for (int reg = 0; reg < 4; ++reg) {
      float ps = acc[r][0][reg] * as_[0] + acc[r][1][reg] * as_[1] +
                 acc[r][2][reg] * as_[2] + acc[r][3][reg] * as_[3];
      float pd = acc[r][0][reg] * ad_[0] + acc[r][1][reg] * ad_[1] +
                 acc[r][2][reg] * ad_[2] + acc[r][3][reg] * ad_[3];
#pragma unroll
      for (int d = 1; d < 16; d <<= 1) {
        ps += __shfl_xor(ps, d, 64);
        pd += __shfl_xor(pd, d, 64);
      }
      if (l15 == 0) {
        int row = m0 + r * 16 + lhi * 4 + reg;
        if (row < n_nodes) {
          ssrc[(size_t)row * 4 + wid] = ps;
          sdst[(size_t)row * 4 + wid] = pd;
        }
      }
    }
  }
}

// ---------------------------------------------------------------------------
// CSR build: memset counts -> histogram -> 3-pass multi-block scan -> scatter
// ---------------------------------------------------------------------------
__global__ void hist_kernel(const int* __restrict__ dst, int e, int* counts) {
  int i = blockIdx.x * blockDim.x + threadIdx.x;
  if (i < e) atomicAdd(&counts[dst[i]], 1);
}

#define SCAN_NB 256

// pass 1: per-block chunk sums
__global__ __launch_bounds__(256) void scan_sums(const int* __restrict__ counts,
                                                 int* __restrict__ bsum, int n, int chunk) {
  __shared__ int ws[4];
  int b = blockIdx.x;
  int t = threadIdx.x;
  int lo = b * chunk, hi = min(lo + chunk, n);
  int s = 0;
  for (int i = lo + t; i < hi; i += 256) s += counts[i];
#pragma unroll
  for (int d = 1; d < 64; d <<= 1) s += __shfl_xor(s, d, 64);
  if ((t & 63) == 0) ws[t >> 6] = s;
  __syncthreads();
  if (t == 0) bsum[b] = ws[0] + ws[1] + ws[2] + ws[3];
}

// pass 2: exclusive scan of the 256 block sums (one block)
__global__ __launch_bounds__(256) void scan_bsum(int* __restrict__ bsum,
                                                 int* __restrict__ bbase) {
  __shared__ int ws[4];
  int t = threadIdx.x;
  int lane = t & 63, w = t >> 6;
  int v = bsum[t];
  int incl = v;
#pragma unroll
  for (int d = 1; d < 64; d <<= 1) {
    int x = __shfl_up(incl, d, 64);
    if (lane >= d) incl += x;
  }
  if (lane == 63) ws[w] = incl;
  __syncthreads();
  int base = 0;
  for (int j = 0; j < w; ++j) base += ws[j];
  bbase[t] = base + incl - v;
}

// pass 3: per-chunk sequential scan + global base -> offs & cursor
__global__ __launch_bounds__(256) void scan_apply(const int* __restrict__ counts,
                                                  const int* __restrict__ bbase,
                                                  int* __restrict__ offs,
                                                  int* __restrict__ cursor,
                                                  int n, int chunk, int total) {
  __shared__ int ws[4];
  __shared__ int s_carry;
  int b = blockIdx.x;
  int t = threadIdx.x;
  int lane = t & 63, w = t >> 6;
  int lo = b * chunk, hi = min(lo + chunk, n);
  if (t == 0) s_carry = bbase[b];
  __syncthreads();
  for (int base = lo; base < hi; base += 512) {
    int i0 = base + t * 2;
    int v0 = (i0 < hi) ? counts[i0] : 0;
    int v1 = (i0 + 1 < hi) ? counts[i0 + 1] : 0;
    int s = v0 + v1;
    int incl = s;
#pragma unroll
    for (int d = 1; d < 64; d <<= 1) {
      int x = __shfl_up(incl, d, 64);
      if (lane >= d) incl += x;
    }
    if (lane == 63) ws[w] = incl;
    __syncthreads();
    int carry = s_carry;
    int wb = 0;
    for (int j = 0; j < w; ++j) wb += ws[j];
    int run = carry + wb + incl - s;
    if (i0 < hi) { offs[i0] = run; cursor[i0] = run; }
    if (i0 + 1 < hi) { offs[i0 + 1] = run + v0; cursor[i0 + 1] = run + v0; }
    __syncthreads();
    if (t == 255) s_carry = carry + wb + incl;
    __syncthreads();
  }
  if (b == 0 && t == 0) offs[n] = total;
}

__global__ void scatter_kernel(const int* __restrict__ src, const int* __restrict__ dst,
                               int e, int* cursor, int* __restrict__ csr) {
  int i = blockIdx.x * blockDim.x + threadIdx.x;
  if (i < e) {
    int p = atomicAdd(&cursor[dst[i]], 1);
    csr[p] = src[i];
  }
}

// ---------------------------------------------------------------------------
// Aggregation: one wave per destination node; bf16 z gather.
// Edge loop unrolled x4: batch the index loads, then issue all 8 gathers
// (4 ssrc + 4 z-rows) independently before consuming -> 1/4 the dependent-
// latency chain of the serial loop.
// ---------------------------------------------------------------------------
__global__ __launch_bounds__(256) void aggregate(const unsigned short* __restrict__ zb,
                                                 const float* __restrict__ ssrc,
                                                 const float* __restrict__ sdst,
                                                 const int* __restrict__ offs,
                                                 const int* __restrict__ csr,
                                                 float* __restrict__ out, int n_nodes) {
  int w = blockIdx.x * (blockDim.x >> 6) + (threadIdx.x >> 6);
  if (w >= n_nodes) return;
  int lane = threadIdx.x & 63;
  int head = lane >> 4;
  int beg = offs[w];
  int end = offs[w + 1];
  float sd = sdst[(size_t)w * 4 + head];
  float ax = 0.f, ay = 0.f, az = 0.f, aw = 0.f;
  float den = 0.f;
  for (int e = beg; e < end; e += 4) {
    int srcs[4];
#pragma unroll
    for (int j = 0; j < 4; ++j) {
      int idx = (e + j < end) ? e + j : end - 1;
      srcs[j] = csr[idx];
    }
    float ss[4];
    s16x4 zv[4];
#pragma unroll
    for (int j = 0; j < 4; ++j) {
      ss[j] = ssrc[(size_t)srcs[j] * 4 + head];
      zv[j] = *reinterpret_cast<const s16x4*>(zb + (size_t)srcs[j] * C_OUT + lane * 4);
    }
#pragma unroll
    for (int j = 0; j < 4; ++j) {
      if (e + j < end) {
        float x = ss[j] + sd;
        x = x > 0.f ? x : 0.01f * x;
        float ex = __expf(x);
        den += ex;
        ax += ex * bf2f((unsigned short)zv[j][0]);
        ay += ex * bf2f((unsigned short)zv[j][1]);
        az += ex * bf2f((unsigned short)zv[j][2]);
        aw += ex * bf2f((unsigned short)zv[j][3]);
      }
    }
  }
  float inv = (end > beg) ? 1.f / fmaxf(den, 1e-9f) : 0.f;
  float4 o = make_float4(ax * inv, ay * inv, az * inv, aw * inv);
  *reinterpret_cast<float4*>(out + (size_t)w * C_OUT + lane * 4) = o;
}

// ---------------------------------------------------------------------------
extern "C" void kernel_launch(void* const* d_in, const int* in_sizes, int n_in,
                              void* d_out, int out_size, void* d_ws, size_t ws_size,
                              hipStream_t stream) {
  const float* h    = (const float*)d_in[0];
  const float* Wm   = (const float*)d_in[1];   // (H,OUT,IN) flat = (256,256)
  const float* attn = (const float*)d_in[2];   // (H, 128); only attn[0] used
  const int* e_src  = (const int*)d_in[3];
  const int* e_dst  = (const int*)d_in[4];
  float* out = (float*)d_out;

  const int N = in_sizes[0] / K_IN;
  const int E = in_sizes[3];

  char* p = (char*)d_ws;
  unsigned short* zb = (unsigned short*)p; p += (size_t)N * C_OUT * sizeof(unsigned short);
  float* ssrc = (float*)p; p += (size_t)N * HEADS * sizeof(float);
  float* sdst = (float*)p; p += (size_t)N * HEADS * sizeof(float);
  int* counts = (int*)p;   p += (size_t)N * sizeof(int);          // reused as cursor
  int* offs   = (int*)p;   p += (size_t)(N + 4) * sizeof(int);
  int* csr    = (int*)p;   p += (size_t)E * sizeof(int);
  unsigned short* Wf = (unsigned short*)p; p += 65536 * sizeof(unsigned short);
  int* bsum  = (int*)p;    p += SCAN_NB * sizeof(int);
  int* bbase = (int*)p;    p += SCAN_NB * sizeof(int);

  const int chunk = (N + SCAN_NB - 1) / SCAN_NB;

  // 0) W conversion (tiny, L2-resident)
  hipLaunchKernelGGL(cvt_w, dim3(256), dim3(256), 0, stream, Wm, Wf);

  // 1) z = h @ W^T (bf16 MFMA, fp32 h read + in-register convert) + scores
  hipLaunchKernelGGL(gemm_z, dim3((N + 63) / 64), dim3(256), 0, stream,
                     h, Wf, attn, zb, ssrc, sdst, N);

  // 2) CSR build by destination
  hipMemsetAsync(counts, 0, (size_t)N * sizeof(int), stream);
  hipLaunchKernelGGL(hist_kernel, dim3((E + 255) / 256), dim3(256), 0, stream, e_dst, E, counts);
  hipLaunchKernelGGL(scan_sums, dim3(SCAN_NB), dim3(256), 0, stream, counts, bsum, N, chunk);
  hipLaunchKernelGGL(scan_bsum, dim3(1), dim3(SCAN_NB), 0, stream, bsum, bbase);
  hipLaunchKernelGGL(scan_apply, dim3(SCAN_NB), dim3(256), 0, stream,
                     counts, bbase, offs, counts, N, chunk, E);
  hipLaunchKernelGGL(scatter_kernel, dim3((E + 255) / 256), dim3(256), 0, stream,
                     e_src, e_dst, E, counts, csr);

  // 3) softmax-weighted aggregation, one wave per node
  hipLaunchKernelGGL(aggregate, dim3((N + 3) / 4), dim3(256), 0, stream,
                     zb, ssrc, sdst, offs, csr, out, N);
}

// Round 5
// 425.805 us; speedup vs baseline: 1.9897x; 1.0334x over previous
//
#include <hip/hip_runtime.h>

#define K_IN   256   // IN
#define C_OUT  256   // H*OUT
#define HEADS  4

typedef __attribute__((ext_vector_type(8))) short s16x8;
typedef __attribute__((ext_vector_type(4))) short s16x4;
typedef __attribute__((ext_vector_type(4))) float f32x4;

static __device__ __forceinline__ unsigned short f2bf(float f) {
  union { float f; unsigned u; } v; v.f = f;
  unsigned r = v.u + 0x7FFFu + ((v.u >> 16) & 1u);
  return (unsigned short)(r >> 16);
}
static __device__ __forceinline__ float bf2f(unsigned short u) {
  union { unsigned u; float f; } v; v.u = (unsigned)u << 16;
  return v.f;
}

// ---------------------------------------------------------------------------
// Convert W (fp32, [c=256][k=256], c = head*64+out) into fragment-ordered bf16:
// Wf[((cb*8+ks)*4+s)*512 + lane*8 + j] = W[cb*64+s*16+(lane&15)][ks*32+(lane>>4)*8+j]
// ---------------------------------------------------------------------------
__global__ void cvt_w(const float* __restrict__ Wm, unsigned short* __restrict__ Wf) {
  int idx = blockIdx.x * blockDim.x + threadIdx.x;
  if (idx >= 65536) return;
  int j    = idx & 7;
  int lane = (idx >> 3) & 63;
  int s    = (idx >> 9) & 3;
  int ks   = (idx >> 11) & 7;
  int cb   = (idx >> 14) & 3;
  int c = cb * 64 + s * 16 + (lane & 15);
  int k = ks * 32 + (lane >> 4) * 8 + j;
  Wf[idx] = f2bf(Wm[c * K_IN + k]);
}

// ---------------------------------------------------------------------------
// GEMM: z[n][c] = sum_k h[n][k] * W[c][k] via bf16 MFMA 16x16x32.
// Reads fp32 h directly; converts A-fragments to bf16 in-register.
// Block = 4 waves; tile = 64 nodes x 256 cols; wave w owns head w's 64 cols.
// Epilogue: bf16 z store + in-register attention scores.
// ---------------------------------------------------------------------------
__global__ __launch_bounds__(256) void gemm_z(const float* __restrict__ h,
                                              const unsigned short* __restrict__ Wf,
                                              const float* __restrict__ attn,
                                              unsigned short* __restrict__ zb,
                                              float* __restrict__ ssrc,
                                              float* __restrict__ sdst, int n_nodes) {
  const int wid  = threadIdx.x >> 6;   // col block == head, 0..3
  const int lane = threadIdx.x & 63;
  const int l15  = lane & 15;
  const int lhi  = lane >> 4;          // 0..3
  const int m0   = blockIdx.x * 64;

  f32x4 acc[4][4];
#pragma unroll
  for (int r = 0; r < 4; ++r)
#pragma unroll
    for (int s = 0; s < 4; ++s) acc[r][s] = (f32x4){0.f, 0.f, 0.f, 0.f};

  long long arow[4];
#pragma unroll
  for (int r = 0; r < 4; ++r) {
    int n = m0 + r * 16 + l15;
    if (n > n_nodes - 1) n = n_nodes - 1;
    arow[r] = (long long)n * K_IN;
  }
  const int kbase = lhi * 8;

#pragma unroll
  for (int ks = 0; ks < 8; ++ks) {
    const int k = ks * 32 + kbase;
    s16x8 a[4], b[4];
#pragma unroll
    for (int r = 0; r < 4; ++r) {
      const float4* p = reinterpret_cast<const float4*>(h + arow[r] + k);
      float4 v0 = p[0], v1 = p[1];
      a[r][0] = (short)f2bf(v0.x); a[r][1] = (short)f2bf(v0.y);
      a[r][2] = (short)f2bf(v0.z); a[r][3] = (short)f2bf(v0.w);
      a[r][4] = (short)f2bf(v1.x); a[r][5] = (short)f2bf(v1.y);
      a[r][6] = (short)f2bf(v1.z); a[r][7] = (short)f2bf(v1.w);
    }
#pragma unroll
    for (int s = 0; s < 4; ++s)
      b[s] = *reinterpret_cast<const s16x8*>(Wf + ((wid * 8 + ks) * 4 + s) * 512 + lane * 8);
#pragma unroll
    for (int r = 0; r < 4; ++r)
#pragma unroll
      for (int s = 0; s < 4; ++s)
        acc[r][s] = __builtin_amdgcn_mfma_f32_16x16x32_bf16(a[r], b[s], acc[r][s], 0, 0, 0);
  }

  // ---- epilogue 1: bf16 z store ----
#pragma unroll
  for (int r = 0; r < 4; ++r) {
#pragma unroll
    for (int reg = 0; reg < 4; ++reg) {
      int row = m0 + r * 16 + lhi * 4 + reg;
      if (row < n_nodes) {
#pragma unroll
        for (int s = 0; s < 4; ++s)
          zb[(size_t)row * C_OUT + wid * 64 + s * 16 + l15] = f2bf(acc[r][s][reg]);
      }
    }
  }

  // ---- epilogue 2: attention scores (fp32, in-register) ----
  float as_[4], ad_[4];
#pragma unroll
  for (int s = 0; s < 4; ++s) {
    as_[s] = attn[s * 16 + l15];
    ad_[s] = attn[64 + s * 16 + l15];
  }
#pragma unroll
  for (int r = 0; r < 4; ++r) {
#pragma unroll
    for (int reg = 0; reg < 4; ++reg) {
      float ps = acc[r][0][reg] * as_[0] + acc[r][1][reg] * as_[1] +
                 acc[r][2][reg] * as_[2] + acc[r][3][reg] * as_[3];
      float pd = acc[r][0][reg] * ad_[0] + acc[r][1][reg] * ad_[1] +
                 acc[r][2][reg] * ad_[2] + acc[r][3][reg] * ad_[3];
#pragma unroll
      for (int d = 1; d < 16; d <<= 1) {
        ps += __shfl_xor(ps, d, 64);
        pd += __shfl_xor(pd, d, 64);
      }
      if (l15 == 0) {
        int row = m0 + r * 16 + lhi * 4 + reg;
        if (row < n_nodes) {
          ssrc[(size_t)row * 4 + wid] = ps;
          sdst[(size_t)row * 4 + wid] = pd;
        }
      }
    }
  }
}

// ---------------------------------------------------------------------------
// CSR build: memset counts -> histogram -> 3-pass multi-block scan -> scatter
// ---------------------------------------------------------------------------
__global__ void hist_kernel(const int* __restrict__ dst, int e, int* counts) {
  int i = blockIdx.x * blockDim.x + threadIdx.x;
  if (i < e) atomicAdd(&counts[dst[i]], 1);
}

#define SCAN_NB 256

// pass 1: per-block chunk sums
__global__ __launch_bounds__(256) void scan_sums(const int* __restrict__ counts,
                                                 int* __restrict__ bsum, int n, int chunk) {
  __shared__ int ws[4];
  int b = blockIdx.x;
  int t = threadIdx.x;
  int lo = b * chunk, hi = min(lo + chunk, n);
  int s = 0;
  for (int i = lo + t; i < hi; i += 256) s += counts[i];
#pragma unroll
  for (int d = 1; d < 64; d <<= 1) s += __shfl_xor(s, d, 64);
  if ((t & 63) == 0) ws[t >> 6] = s;
  __syncthreads();
  if (t == 0) bsum[b] = ws[0] + ws[1] + ws[2] + ws[3];
}

// pass 2: exclusive scan of the 256 block sums (one block)
__global__ __launch_bounds__(256) void scan_bsum(int* __restrict__ bsum,
                                                 int* __restrict__ bbase) {
  __shared__ int ws[4];
  int t = threadIdx.x;
  int lane = t & 63, w = t >> 6;
  int v = bsum[t];
  int incl = v;
#pragma unroll
  for (int d = 1; d < 64; d <<= 1) {
    int x = __shfl_up(incl, d, 64);
    if (lane >= d) incl += x;
  }
  if (lane == 63) ws[w] = incl;
  __syncthreads();
  int base = 0;
  for (int j = 0; j < w; ++j) base += ws[j];
  bbase[t] = base + incl - v;
}

// pass 3: per-chunk sequential scan + global base -> offs & cursor
__global__ __launch_bounds__(256) void scan_apply(const int* __restrict__ counts,
                                                  const int* __restrict__ bbase,
                                                  int* __restrict__ offs,
                                                  int* __restrict__ cursor,
                                                  int n, int chunk, int total) {
  __shared__ int ws[4];
  __shared__ int s_carry;
  int b = blockIdx.x;
  int t = threadIdx.x;
  int lane = t & 63, w = t >> 6;
  int lo = b * chunk, hi = min(lo + chunk, n);
  if (t == 0) s_carry = bbase[b];
  __syncthreads();
  for (int base = lo; base < hi; base += 512) {
    int i0 = base + t * 2;
    int v0 = (i0 < hi) ? counts[i0] : 0;
    int v1 = (i0 + 1 < hi) ? counts[i0 + 1] : 0;
    int s = v0 + v1;
    int incl = s;
#pragma unroll
    for (int d = 1; d < 64; d <<= 1) {
      int x = __shfl_up(incl, d, 64);
      if (lane >= d) incl += x;
    }
    if (lane == 63) ws[w] = incl;
    __syncthreads();
    int carry = s_carry;
    int wb = 0;
    for (int j = 0; j < w; ++j) wb += ws[j];
    int run = carry + wb + incl - s;
    if (i0 < hi) { offs[i0] = run; cursor[i0] = run; }
    if (i0 + 1 < hi) { offs[i0 + 1] = run + v0; cursor[i0 + 1] = run + v0; }
    __syncthreads();
    if (t == 255) s_carry = carry + wb + incl;
    __syncthreads();
  }
  if (b == 0 && t == 0) offs[n] = total;
}

__global__ void scatter_kernel(const int* __restrict__ src, const int* __restrict__ dst,
                               int e, int* cursor, int* __restrict__ csr) {
  int i = blockIdx.x * blockDim.x + threadIdx.x;
  if (i < e) {
    int p = atomicAdd(&cursor[dst[i]], 1);
    csr[p] = src[i];
  }
}

// ---------------------------------------------------------------------------
// Aggregation: one wave per destination node; bf16 z gather.
// Edge loop unrolled x8: 8 csr index loads, then 16 independent gathers
// (8 ssrc + 8 z-rows) in flight before any consume. Clamped tail entries
// re-read the last row (L1 hit) and contribute ex=0.
// out stored nontemporal (single-use, keep L2 for the z table); csr loaded
// nontemporal (streamed once).
// ---------------------------------------------------------------------------
__global__ __launch_bounds__(256) void aggregate(const unsigned short* __restrict__ zb,
                                                 const float* __restrict__ ssrc,
                                                 const float* __restrict__ sdst,
                                                 const int* __restrict__ offs,
                                                 const int* __restrict__ csr,
                                                 float* __restrict__ out, int n_nodes) {
  int w = blockIdx.x * (blockDim.x >> 6) + (threadIdx.x >> 6);
  if (w >= n_nodes) return;
  int lane = threadIdx.x & 63;
  int head = lane >> 4;
  int beg = offs[w];
  int end = offs[w + 1];
  float sd = sdst[(size_t)w * 4 + head];
  float ax = 0.f, ay = 0.f, az = 0.f, aw = 0.f;
  float den = 0.f;
  for (int e = beg; e < end; e += 8) {
    int srcs[8];
#pragma unroll
    for (int j = 0; j < 8; ++j) {
      int idx = e + j;
      if (idx >= end) idx = end - 1;
      srcs[j] = __builtin_nontemporal_load(csr + idx);
    }
    float ss[8];
    s16x4 zv[8];
#pragma unroll
    for (int j = 0; j < 8; ++j)
      ss[j] = ssrc[(size_t)srcs[j] * 4 + head];
#pragma unroll
    for (int j = 0; j < 8; ++j)
      zv[j] = *reinterpret_cast<const s16x4*>(zb + (size_t)srcs[j] * C_OUT + lane * 4);
#pragma unroll
    for (int j = 0; j < 8; ++j) {
      float x = ss[j] + sd;
      x = x > 0.f ? x : 0.01f * x;
      float ex = __expf(x);
      ex = (e + j < end) ? ex : 0.f;
      den += ex;
      ax += ex * bf2f((unsigned short)zv[j][0]);
      ay += ex * bf2f((unsigned short)zv[j][1]);
      az += ex * bf2f((unsigned short)zv[j][2]);
      aw += ex * bf2f((unsigned short)zv[j][3]);
    }
  }
  float inv = (end > beg) ? 1.f / fmaxf(den, 1e-9f) : 0.f;
  f32x4 o = {ax * inv, ay * inv, az * inv, aw * inv};
  __builtin_nontemporal_store(o, reinterpret_cast<f32x4*>(out + (size_t)w * C_OUT + lane * 4));
}

// ---------------------------------------------------------------------------
extern "C" void kernel_launch(void* const* d_in, const int* in_sizes, int n_in,
                              void* d_out, int out_size, void* d_ws, size_t ws_size,
                              hipStream_t stream) {
  const float* h    = (const float*)d_in[0];
  const float* Wm   = (const float*)d_in[1];   // (H,OUT,IN) flat = (256,256)
  const float* attn = (const float*)d_in[2];   // (H, 128); only attn[0] used
  const int* e_src  = (const int*)d_in[3];
  const int* e_dst  = (const int*)d_in[4];
  float* out = (float*)d_out;

  const int N = in_sizes[0] / K_IN;
  const int E = in_sizes[3];

  char* p = (char*)d_ws;
  unsigned short* zb = (unsigned short*)p; p += (size_t)N * C_OUT * sizeof(unsigned short);
  float* ssrc = (float*)p; p += (size_t)N * HEADS * sizeof(float);
  float* sdst = (float*)p; p += (size_t)N * HEADS * sizeof(float);
  int* counts = (int*)p;   p += (size_t)N * sizeof(int);          // reused as cursor
  int* offs   = (int*)p;   p += (size_t)(N + 4) * sizeof(int);
  int* csr    = (int*)p;   p += (size_t)E * sizeof(int);
  unsigned short* Wf = (unsigned short*)p; p += 65536 * sizeof(unsigned short);
  int* bsum  = (int*)p;    p += SCAN_NB * sizeof(int);
  int* bbase = (int*)p;    p += SCAN_NB * sizeof(int);

  const int chunk = (N + SCAN_NB - 1) / SCAN_NB;

  // 0) W conversion (tiny, L2-resident)
  hipLaunchKernelGGL(cvt_w, dim3(256), dim3(256), 0, stream, Wm, Wf);

  // 1) z = h @ W^T (bf16 MFMA, fp32 h read + in-register convert) + scores
  hipLaunchKernelGGL(gemm_z, dim3((N + 63) / 64), dim3(256), 0, stream,
                     h, Wf, attn, zb, ssrc, sdst, N);

  // 2) CSR build by destination
  hipMemsetAsync(counts, 0, (size_t)N * sizeof(int), stream);
  hipLaunchKernelGGL(hist_kernel, dim3((E + 255) / 256), dim3(256), 0, stream, e_dst, E, counts);
  hipLaunchKernelGGL(scan_sums, dim3(SCAN_NB), dim3(256), 0, stream, counts, bsum, N, chunk);
  hipLaunchKernelGGL(scan_bsum, dim3(1), dim3(SCAN_NB), 0, stream, bsum, bbase);
  hipLaunchKernelGGL(scan_apply, dim3(SCAN_NB), dim3(256), 0, stream,
                     counts, bbase, offs, counts, N, chunk, E);
  hipLaunchKernelGGL(scatter_kernel, dim3((E + 255) / 256), dim3(256), 0, stream,
                     e_src, e_dst, E, counts, csr);

  // 3) softmax-weighted aggregation, one wave per node
  hipLaunchKernelGGL(aggregate, dim3((N + 3) / 4), dim3(256), 0, stream,
                     zb, ssrc, sdst, offs, csr, out, N);
}